// Round 1
// baseline (4273.908 us; speedup 1.0000x reference)
//
#include <hip/hip_runtime.h>
#include <hip/hip_bf16.h>

#define B_   32
#define T_   128
#define H_   700
#define HP   704
#define E_   100
#define G3   2100
#define V_   32000
#define DY_  200
#define DZ_  500
#define KP   704
#define NBLK 175
#define JW   4

typedef __attribute__((ext_vector_type(8))) short bf16x8;
typedef __attribute__((ext_vector_type(4))) float f32x4;

// ---------------- grid barrier (sense-reversing, device scope) ----------------
__device__ __forceinline__ void gbar(unsigned* cnt, unsigned* gen) {
    __syncthreads();
    if (threadIdx.x == 0) {
        __threadfence();  // release: block's prior writes visible device-wide
        unsigned g0 = __hip_atomic_load(gen, __ATOMIC_RELAXED, __HIP_MEMORY_SCOPE_AGENT);
        unsigned a  = __hip_atomic_fetch_add(cnt, 1u, __ATOMIC_ACQ_REL, __HIP_MEMORY_SCOPE_AGENT);
        if (a == (unsigned)(NBLK - 1)) {
            __hip_atomic_store(cnt, 0u, __ATOMIC_RELAXED, __HIP_MEMORY_SCOPE_AGENT);
            __hip_atomic_fetch_add(gen, 1u, __ATOMIC_ACQ_REL, __HIP_MEMORY_SCOPE_AGENT);
        } else {
            while (__hip_atomic_load(gen, __ATOMIC_ACQUIRE, __HIP_MEMORY_SCOPE_AGENT) == g0)
                __builtin_amdgcn_s_sleep(2);
        }
        __threadfence();  // acquire: invalidate stale lines
    }
    __syncthreads();
}

// ---------------- proj_W [700][32000] fp32 -> Wb [32000][704] bf16 (transposed, K-padded) ----------------
__global__ __launch_bounds__(256)
void wconv_kernel(const float* __restrict__ W, __hip_bfloat16* __restrict__ Wb) {
    __shared__ float tile[32][33];
    const int n0 = blockIdx.x * 32, k0 = blockIdx.y * 32;
    const int tx = threadIdx.x, ty = threadIdx.y;  // 32, 8
    #pragma unroll
    for (int i = 0; i < 4; ++i) {
        int k = k0 + ty + 8 * i;
        float v = (k < H_) ? W[(size_t)k * V_ + n0 + tx] : 0.0f;
        tile[ty + 8 * i][tx] = v;
    }
    __syncthreads();
    #pragma unroll
    for (int i = 0; i < 4; ++i) {
        int nn = ty + 8 * i;
        Wb[(size_t)(n0 + nn) * KP + k0 + tx] = __float2bfloat16(tile[tx][nn]);
    }
}

// ---------------- xp[b*T+t][2100] = emb[dec[b][t]] @ gru1_k + gru1_b[0] ----------------
__global__ __launch_bounds__(256)
void xp_kernel(const int* __restrict__ di, const float* __restrict__ emb,
               const float* __restrict__ gk, const float* __restrict__ gb,
               float* __restrict__ xp) {
    __shared__ float xl[E_];
    const int row = blockIdx.x;
    const int tid = threadIdx.x;
    if (tid < E_) xl[tid] = emb[(size_t)di[row] * E_ + tid];
    __syncthreads();
    for (int j4 = tid; j4 < G3 / 4; j4 += 256) {
        int j = j4 * 4;
        float4 a = *(const float4*)&gb[j];
        #pragma unroll 4
        for (int k = 0; k < E_; ++k) {
            float xv = xl[k];
            float4 wv = *(const float4*)&gk[(size_t)k * G3 + j];
            a.x += xv * wv.x; a.y += xv * wv.y; a.z += xv * wv.z; a.w += xv * wv.w;
        }
        *(float4*)&xp[(size_t)row * G3 + j] = a;
    }
}

// ---------------- persistent GRU recurrence ----------------
// grid = 175 blocks x 256 threads, 1 block/CU (150KB LDS) -> co-resident.
// block owns j0..j0+3 (4 gate indices) => 12 rk columns, all 32 batch rows.
__global__ __launch_bounds__(256)
void gru_kernel(const float* __restrict__ labels, const float* __restrict__ zin,
                const float* __restrict__ W1, const float* __restrict__ b1,
                const float* __restrict__ xp, const float* __restrict__ mask,
                const float* __restrict__ rk, const float* __restrict__ gb,
                float* __restrict__ hbuf, __hip_bfloat16* __restrict__ g_out,
                unsigned* __restrict__ bar) {
    extern __shared__ float sm[];
    float* h_lds  = sm;               // 32*704            = 22528 floats (swizzled)
    float* rk_lds = sm + 22528;       // 12*704            =  8448 floats
    float* part   = sm + 30976;       // 16*384            =  6144 floats
    float* hp_lds = sm + 37120;       // 384 floats

    const int tid = threadIdx.x;
    const int blk = blockIdx.x;
    const int j0  = blk * JW;

    // stage rk columns into LDS once (zero K-pad)
    for (int e = tid; e < 12 * HP; e += 256) {
        int c = e % 12, k = e / 12;
        int gcol = (c >> 2) * H_ + j0 + (c & 3);
        float v = (k < H_) ? rk[(size_t)k * G3 + gcol] : 0.0f;
        rk_lds[c * HP + k] = v;
    }

    // init h0 into hbuf[0]
    if (tid < 128) {
        int b = tid >> 2, jj = tid & 3, j = j0 + jj;
        float v = (j < DY_) ? labels[b] * W1[j] + b1[j] : zin[b * DZ_ + (j - DY_)];
        hbuf[b * HP + j] = v;
    }
    if (blk == 0) {  // zero K-pads of both h buffers
        int buf = tid >> 7, rem = tid & 127, b = rem >> 2, p = rem & 3;
        hbuf[buf * B_ * HP + b * HP + H_ + p] = 0.0f;
    }
    gbar(bar, bar + 1);

    const int kc = tid >> 4;          // 0..15 : K-chunk of 44
    const int u  = tid & 15;
    const int b0 = (u >> 1) * 4;      // 4-row tile
    const int c0 = (u & 1) * 6;       // 6-col tile
    const int kbeg = kc * 44;

    for (int step = 0; step < T_; ++step) {
        const int cur = step & 1, nxt = cur ^ 1;
        const float* hg = hbuf + cur * B_ * HP;

        // stage h (fp32) into LDS with XOR swizzle on bits 2..4 keyed by (b>>2)
        for (int e4 = tid; e4 < (B_ * HP) / 4; e4 += 256) {
            int b = e4 / (HP / 4);
            int k4 = (e4 % (HP / 4)) * 4;
            float4 v = *(const float4*)&hg[b * HP + k4];
            int idx = (b * HP + k4) ^ ((b >> 2) << 2);
            *(float4*)&h_lds[idx] = v;
        }
        __syncthreads();

        // partial dots: 4 rows x 6 cols per thread over 44 K
        float acc[4][6];
        #pragma unroll
        for (int i = 0; i < 4; ++i)
            #pragma unroll
            for (int j = 0; j < 6; ++j) acc[i][j] = 0.0f;

        for (int k = kbeg; k < kbeg + 44; k += 4) {
            float4 hv[4], rv[6];
            #pragma unroll
            for (int i = 0; i < 4; ++i) {
                int b = b0 + i;
                hv[i] = *(const float4*)&h_lds[(b * HP + k) ^ ((b >> 2) << 2)];
            }
            #pragma unroll
            for (int j = 0; j < 6; ++j)
                rv[j] = *(const float4*)&rk_lds[(c0 + j) * HP + k];
            #pragma unroll
            for (int i = 0; i < 4; ++i)
                #pragma unroll
                for (int j = 0; j < 6; ++j)
                    acc[i][j] += hv[i].x * rv[j].x + hv[i].y * rv[j].y
                               + hv[i].z * rv[j].z + hv[i].w * rv[j].w;
        }
        #pragma unroll
        for (int i = 0; i < 4; ++i)
            #pragma unroll
            for (int j = 0; j < 6; ++j)
                part[kc * 384 + (b0 + i) * 12 + (c0 + j)] = acc[i][j];
        __syncthreads();

        // reduce K-chunks
        for (int d = tid; d < 384; d += 256) {
            float s = 0.0f;
            #pragma unroll
            for (int q = 0; q < 16; ++q) s += part[q * 384 + d];
            hp_lds[d] = s;
        }
        __syncthreads();

        // gates: 128 (b,j) pairs
        if (tid < 128) {
            int b = tid >> 2, jj = tid & 3, j = j0 + jj;
            float hpz = hp_lds[b * 12 + jj]      + gb[G3 + j];
            float hpr = hp_lds[b * 12 + 4 + jj]  + gb[G3 + H_ + j];
            float hph = hp_lds[b * 12 + 8 + jj]  + gb[G3 + 2 * H_ + j];
            size_t xrow = (size_t)(b * T_ + step) * G3;
            float xz = xp[xrow + j], xr = xp[xrow + H_ + j], xh = xp[xrow + 2 * H_ + j];
            float hold = h_lds[(b * HP + j) ^ ((b >> 2) << 2)];
            float zg = 1.0f / (1.0f + expf(-(xz + hpz)));
            float rg = 1.0f / (1.0f + expf(-(xr + hpr)));
            float hh = tanhf(xh + rg * hph);
            float hn = zg * hold + (1.0f - zg) * hh;
            hbuf[nxt * B_ * HP + b * HP + j] = hn;
            float mv = mask[(size_t)(b * T_ + step) * H_ + j];
            g_out[(size_t)(b * T_ + step) * KP + j] = __float2bfloat16(hn * mv);
        }
        if (step != T_ - 1) gbar(bar, bar + 1);
    }
}

// ---------------- projection GEMM: C[4096][32000] = g[4096][704] @ Wb[32000][704]^T + bias ----------------
__global__ __launch_bounds__(256)
void gemm_kernel(const __hip_bfloat16* __restrict__ A, const __hip_bfloat16* __restrict__ Bw,
                 const float* __restrict__ bias, float* __restrict__ C) {
    __shared__ alignas(16) unsigned short As[128][72];
    __shared__ alignas(16) unsigned short Bs[128][72];
    const int tid = threadIdx.x;
    const int bn = blockIdx.x, bm = blockIdx.y;
    const int rowbase = bm * 128, colbase = bn * 128;
    const int lane = tid & 63, w = tid >> 6;
    const int wm = w >> 1, wn = w & 1;
    const int lr = lane & 15, lkg = lane >> 4;

    f32x4 acc[4][4];
    #pragma unroll
    for (int i = 0; i < 4; ++i)
        #pragma unroll
        for (int j = 0; j < 4; ++j) acc[i][j] = (f32x4){0.f, 0.f, 0.f, 0.f};

    const int srow = tid >> 3, skk = (tid & 7) * 8;

    for (int kt = 0; kt < 11; ++kt) {
        const int k0 = kt * 64;
        __syncthreads();
        #pragma unroll
        for (int i = 0; i < 4; ++i) {
            int r = srow + i * 32;
            *(uint4*)&As[r][skk] = *(const uint4*)&A[(size_t)(rowbase + r) * KP + k0 + skk];
            *(uint4*)&Bs[r][skk] = *(const uint4*)&Bw[(size_t)(colbase + r) * KP + k0 + skk];
        }
        __syncthreads();
        #pragma unroll
        for (int ks = 0; ks < 2; ++ks) {
            bf16x8 af[4], bf[4];
            #pragma unroll
            for (int i = 0; i < 4; ++i)
                af[i] = *(const bf16x8*)&As[wm * 64 + i * 16 + lr][ks * 32 + lkg * 8];
            #pragma unroll
            for (int j = 0; j < 4; ++j)
                bf[j] = *(const bf16x8*)&Bs[wn * 64 + j * 16 + lr][ks * 32 + lkg * 8];
            #pragma unroll
            for (int i = 0; i < 4; ++i)
                #pragma unroll
                for (int j = 0; j < 4; ++j)
                    acc[i][j] = __builtin_amdgcn_mfma_f32_16x16x32_bf16(af[i], bf[j], acc[i][j], 0, 0, 0);
        }
    }

    float bv[4];
    #pragma unroll
    for (int j = 0; j < 4; ++j) bv[j] = bias[colbase + wn * 64 + j * 16 + lr];
    #pragma unroll
    for (int i = 0; i < 4; ++i) {
        int grow0 = rowbase + wm * 64 + i * 16 + lkg * 4;
        #pragma unroll
        for (int j = 0; j < 4; ++j) {
            int gcol = colbase + wn * 64 + j * 16 + lr;
            #pragma unroll
            for (int r = 0; r < 4; ++r)
                C[(size_t)(grow0 + r) * V_ + gcol] = acc[i][j][r] + bv[j];
        }
    }
}

extern "C" void kernel_launch(void* const* d_in, const int* in_sizes, int n_in,
                              void* d_out, int out_size, void* d_ws, size_t ws_size,
                              hipStream_t stream) {
    const float* labels = (const float*)d_in[0];
    const float* z      = (const float*)d_in[1];
    const int*   di     = (const int*)d_in[2];
    const float* mask   = (const float*)d_in[3];
    const float* emb    = (const float*)d_in[4];
    const float* W1     = (const float*)d_in[5];
    const float* b1     = (const float*)d_in[6];
    const float* g1k    = (const float*)d_in[7];
    const float* g1rk   = (const float*)d_in[8];
    const float* g1b    = (const float*)d_in[9];
    const float* pW     = (const float*)d_in[10];
    const float* pb     = (const float*)d_in[11];

    char* ws = (char*)d_ws;
    float*           xp   = (float*)ws;                         // 34,406,400 B
    __hip_bfloat16*  g    = (__hip_bfloat16*)(ws + 34406400);   //  5,767,168 B
    __hip_bfloat16*  Wb   = (__hip_bfloat16*)(ws + 40173568);   // 45,056,000 B
    float*           hbuf = (float*)(ws + 85229568);            //    180,224 B
    unsigned*        bar  = (unsigned*)(ws + 85409792);         //          8 B

    hipMemsetAsync(bar, 0, 8, stream);

    wconv_kernel<<<dim3(1000, 22), dim3(32, 8), 0, stream>>>(pW, Wb);
    xp_kernel<<<dim3(4096), 256, 0, stream>>>(di, emb, g1k, g1b, xp);

    hipFuncSetAttribute((const void*)gru_kernel,
                        hipFuncAttributeMaxDynamicSharedMemorySize, 150016);
    gru_kernel<<<dim3(NBLK), 256, 150016, stream>>>(labels, z, W1, b1, xp, mask,
                                                    g1rk, g1b, hbuf, g, bar);

    gemm_kernel<<<dim3(250, 32), 256, 0, stream>>>(g, Wb, pb, (float*)d_out);
}

// Round 2
// 2310.396 us; speedup vs baseline: 1.8499x; 1.8499x over previous
//
#include <hip/hip_runtime.h>
#include <hip/hip_bf16.h>

#define B_   32
#define T_   128
#define H_   700
#define HP   704
#define E_   100
#define G3   2100
#define V_   32000
#define DY_  200
#define DZ_  500
#define KP   704
#define NBLK 175
#define JW   4
#define FSTR 16   // flag stride in uints (64B) to give each flag its own cacheline

typedef __attribute__((ext_vector_type(8))) short bf16x8;
typedef __attribute__((ext_vector_type(4))) float f32x4;

__device__ __forceinline__ unsigned ld_flag(const unsigned* p) {
    return __hip_atomic_load(p, __ATOMIC_RELAXED, __HIP_MEMORY_SCOPE_AGENT);
}
__device__ __forceinline__ void st_flag(unsigned* p, unsigned v) {
    __hip_atomic_store(p, v, __ATOMIC_RELAXED, __HIP_MEMORY_SCOPE_AGENT);
}
__device__ __forceinline__ void st_h(float* p, float v) {
    __hip_atomic_store(p, v, __ATOMIC_RELAXED, __HIP_MEMORY_SCOPE_AGENT);
}

// ---------------- proj_W [700][32000] fp32 -> Wb [32000][704] bf16 (transposed, K-padded) ----------------
__global__ __launch_bounds__(256)
void wconv_kernel(const float* __restrict__ W, __hip_bfloat16* __restrict__ Wb) {
    __shared__ float tile[32][33];
    const int n0 = blockIdx.x * 32, k0 = blockIdx.y * 32;
    const int tx = threadIdx.x, ty = threadIdx.y;  // 32, 8
    #pragma unroll
    for (int i = 0; i < 4; ++i) {
        int k = k0 + ty + 8 * i;
        float v = (k < H_) ? W[(size_t)k * V_ + n0 + tx] : 0.0f;
        tile[ty + 8 * i][tx] = v;
    }
    __syncthreads();
    #pragma unroll
    for (int i = 0; i < 4; ++i) {
        int nn = ty + 8 * i;
        Wb[(size_t)(n0 + nn) * KP + k0 + tx] = __float2bfloat16(tile[tx][nn]);
    }
}

// ---------------- xp[b*T+t][2100] = emb[dec[b][t]] @ gru1_k + gru1_b[0] ----------------
__global__ __launch_bounds__(256)
void xp_kernel(const int* __restrict__ di, const float* __restrict__ emb,
               const float* __restrict__ gk, const float* __restrict__ gb,
               float* __restrict__ xp) {
    __shared__ float xl[E_];
    const int row = blockIdx.x;
    const int tid = threadIdx.x;
    if (tid < E_) xl[tid] = emb[(size_t)di[row] * E_ + tid];
    __syncthreads();
    for (int j4 = tid; j4 < G3 / 4; j4 += 256) {
        int j = j4 * 4;
        float4 a = *(const float4*)&gb[j];
        #pragma unroll 4
        for (int k = 0; k < E_; ++k) {
            float xv = xl[k];
            float4 wv = *(const float4*)&gk[(size_t)k * G3 + j];
            a.x += xv * wv.x; a.y += xv * wv.y; a.z += xv * wv.z; a.w += xv * wv.w;
        }
        *(float4*)&xp[(size_t)row * G3 + j] = a;
    }
}

// ---------------- persistent GRU recurrence ----------------
// grid = 175 blocks x 256 threads, 1 block/CU (150KB LDS) -> co-resident.
// block owns j0..j0+3 (4 gate indices) => 12 rk columns, all 32 batch rows.
// Sync: per-block monotonic flags (uncontended agent stores) + parallel spin,
// replacing the serialized fetch_add barrier.
__global__ __launch_bounds__(256)
void gru_kernel(const float* __restrict__ labels, const float* __restrict__ zin,
                const float* __restrict__ W1, const float* __restrict__ b1,
                const float* __restrict__ xp, const float* __restrict__ mask,
                const float* __restrict__ rk, const float* __restrict__ gb,
                float* __restrict__ hbuf, __hip_bfloat16* __restrict__ g_out,
                unsigned* __restrict__ flags) {
    extern __shared__ float sm[];
    float* h_lds  = sm;               // 32*704            = 22528 floats (swizzled)
    float* rk_lds = sm + 22528;       // 12*704            =  8448 floats
    float* part   = sm + 30976;       // 16*384            =  6144 floats
    float* hp_lds = sm + 37120;       // 384 floats

    const int tid = threadIdx.x;
    const int blk = blockIdx.x;
    const int j0  = blk * JW;

    // stage rk columns into LDS once (zero K-pad)
    for (int e = tid; e < 12 * HP; e += 256) {
        int c = e % 12, k = e / 12;
        int gcol = (c >> 2) * H_ + j0 + (c & 3);
        float v = (k < H_) ? rk[(size_t)k * G3 + gcol] : 0.0f;
        rk_lds[c * HP + k] = v;
    }

    // init h0 into hbuf[0] (agent-scope stores -> visible at coherence point)
    if (tid < 128) {
        int b = tid >> 2, jj = tid & 3, j = j0 + jj;
        float v = (j < DY_) ? labels[b] * W1[j] + b1[j] : zin[b * DZ_ + (j - DY_)];
        st_h(&hbuf[b * HP + j], v);
    }
    if (blk == 0) {  // zero K-pads of both h buffers
        int buf = tid >> 7, rem = tid & 127, b = rem >> 2, p = rem & 3;
        st_h(&hbuf[buf * B_ * HP + b * HP + H_ + p], 0.0f);
    }

    // hoist step-invariant gate biases into registers
    float bz = 0.f, brr = 0.f, bh = 0.f;
    if (tid < 128) {
        int j = j0 + (tid & 3);
        bz  = gb[G3 + j];
        brr = gb[G3 + H_ + j];
        bh  = gb[G3 + 2 * H_ + j];
    }

    __syncthreads();                         // drains vmcnt(0): h0 stores complete
    if (tid == 0) st_flag(&flags[blk * FSTR], 1u);

    const int kc = tid >> 4;          // 0..15 : K-chunk of 44
    const int u  = tid & 15;
    const int b0 = (u >> 1) * 4;      // 4-row tile
    const int c0 = (u & 1) * 6;       // 6-col tile
    const int kbeg = kc * 44;

    for (int step = 0; step < T_; ++step) {
        const int cur = step & 1, nxt = cur ^ 1;
        const float* hg = hbuf + cur * B_ * HP;

        // prefetch step-dependent immutable inputs (safe pre-invalidate)
        float xz = 0.f, xr = 0.f, xh = 0.f, mv = 0.f;
        if (tid < 128) {
            int b = tid >> 2, j = j0 + (tid & 3);
            size_t xrow = (size_t)(b * T_ + step) * G3;
            xz = xp[xrow + j];
            xr = xp[xrow + H_ + j];
            xh = xp[xrow + 2 * H_ + j];
            mv = mask[(size_t)(b * T_ + step) * H_ + j];
        }

        // wait until every block published h_step (parallel, uncontended spins)
        if (tid < NBLK) {
            while (ld_flag(&flags[tid * FSTR]) < (unsigned)(step + 1))
                __builtin_amdgcn_s_sleep(1);
        }
        __syncthreads();
        if (tid == 0) __threadfence();   // invalidate L1+L2 so h loads are fresh
        __syncthreads();

        // stage h (fp32) into LDS with XOR swizzle on bits 2..4 keyed by (b>>2)
        for (int e4 = tid; e4 < (B_ * HP) / 4; e4 += 256) {
            int b = e4 / (HP / 4);
            int k4 = (e4 % (HP / 4)) * 4;
            float4 v = *(const float4*)&hg[b * HP + k4];
            int idx = (b * HP + k4) ^ ((b >> 2) << 2);
            *(float4*)&h_lds[idx] = v;
        }
        __syncthreads();

        // partial dots: 4 rows x 6 cols per thread over 44 K
        float acc[4][6];
        #pragma unroll
        for (int i = 0; i < 4; ++i)
            #pragma unroll
            for (int j = 0; j < 6; ++j) acc[i][j] = 0.0f;

        for (int k = kbeg; k < kbeg + 44; k += 4) {
            float4 hv[4], rv[6];
            #pragma unroll
            for (int i = 0; i < 4; ++i) {
                int b = b0 + i;
                hv[i] = *(const float4*)&h_lds[(b * HP + k) ^ ((b >> 2) << 2)];
            }
            #pragma unroll
            for (int j = 0; j < 6; ++j)
                rv[j] = *(const float4*)&rk_lds[(c0 + j) * HP + k];
            #pragma unroll
            for (int i = 0; i < 4; ++i)
                #pragma unroll
                for (int j = 0; j < 6; ++j)
                    acc[i][j] += hv[i].x * rv[j].x + hv[i].y * rv[j].y
                               + hv[i].z * rv[j].z + hv[i].w * rv[j].w;
        }
        #pragma unroll
        for (int i = 0; i < 4; ++i)
            #pragma unroll
            for (int j = 0; j < 6; ++j)
                part[kc * 384 + (b0 + i) * 12 + (c0 + j)] = acc[i][j];
        __syncthreads();

        // reduce K-chunks
        for (int d = tid; d < 384; d += 256) {
            float s = 0.0f;
            #pragma unroll
            for (int q = 0; q < 16; ++q) s += part[q * 384 + d];
            hp_lds[d] = s;
        }
        __syncthreads();

        // gates: 128 (b,j) pairs
        if (tid < 128) {
            int b = tid >> 2, jj = tid & 3, j = j0 + jj;
            float hpz = hp_lds[b * 12 + jj]      + bz;
            float hpr = hp_lds[b * 12 + 4 + jj]  + brr;
            float hph = hp_lds[b * 12 + 8 + jj]  + bh;
            float hold = h_lds[(b * HP + j) ^ ((b >> 2) << 2)];
            float zg = 1.0f / (1.0f + expf(-(xz + hpz)));
            float rg = 1.0f / (1.0f + expf(-(xr + hpr)));
            float hh = tanhf(xh + rg * hph);
            float hn = zg * hold + (1.0f - zg) * hh;
            st_h(&hbuf[nxt * B_ * HP + b * HP + j], hn);
            g_out[(size_t)(b * T_ + step) * KP + j] = __float2bfloat16(hn * mv);
        }
        __syncthreads();                    // drains vmcnt(0): h stores complete
        if (tid == 0) st_flag(&flags[blk * FSTR], (unsigned)(step + 2));
    }
}

// ---------------- projection GEMM: C[4096][32000] = g[4096][704] @ Wb[32000][704]^T + bias ----------------
__global__ __launch_bounds__(256)
void gemm_kernel(const __hip_bfloat16* __restrict__ A, const __hip_bfloat16* __restrict__ Bw,
                 const float* __restrict__ bias, float* __restrict__ C) {
    __shared__ alignas(16) unsigned short As[128][72];
    __shared__ alignas(16) unsigned short Bs[128][72];
    const int tid = threadIdx.x;
    const int bn = blockIdx.x, bm = blockIdx.y;
    const int rowbase = bm * 128, colbase = bn * 128;
    const int lane = tid & 63, w = tid >> 6;
    const int wm = w >> 1, wn = w & 1;
    const int lr = lane & 15, lkg = lane >> 4;

    f32x4 acc[4][4];
    #pragma unroll
    for (int i = 0; i < 4; ++i)
        #pragma unroll
        for (int j = 0; j < 4; ++j) acc[i][j] = (f32x4){0.f, 0.f, 0.f, 0.f};

    const int srow = tid >> 3, skk = (tid & 7) * 8;

    for (int kt = 0; kt < 11; ++kt) {
        const int k0 = kt * 64;
        __syncthreads();
        #pragma unroll
        for (int i = 0; i < 4; ++i) {
            int r = srow + i * 32;
            *(uint4*)&As[r][skk] = *(const uint4*)&A[(size_t)(rowbase + r) * KP + k0 + skk];
            *(uint4*)&Bs[r][skk] = *(const uint4*)&Bw[(size_t)(colbase + r) * KP + k0 + skk];
        }
        __syncthreads();
        #pragma unroll
        for (int ks = 0; ks < 2; ++ks) {
            bf16x8 af[4], bf[4];
            #pragma unroll
            for (int i = 0; i < 4; ++i)
                af[i] = *(const bf16x8*)&As[wm * 64 + i * 16 + lr][ks * 32 + lkg * 8];
            #pragma unroll
            for (int j = 0; j < 4; ++j)
                bf[j] = *(const bf16x8*)&Bs[wn * 64 + j * 16 + lr][ks * 32 + lkg * 8];
            #pragma unroll
            for (int i = 0; i < 4; ++i)
                #pragma unroll
                for (int j = 0; j < 4; ++j)
                    acc[i][j] = __builtin_amdgcn_mfma_f32_16x16x32_bf16(af[i], bf[j], acc[i][j], 0, 0, 0);
        }
    }

    float bv[4];
    #pragma unroll
    for (int j = 0; j < 4; ++j) bv[j] = bias[colbase + wn * 64 + j * 16 + lr];
    #pragma unroll
    for (int i = 0; i < 4; ++i) {
        int grow0 = rowbase + wm * 64 + i * 16 + lkg * 4;
        #pragma unroll
        for (int j = 0; j < 4; ++j) {
            int gcol = colbase + wn * 64 + j * 16 + lr;
            #pragma unroll
            for (int r = 0; r < 4; ++r)
                C[(size_t)(grow0 + r) * V_ + gcol] = acc[i][j][r] + bv[j];
        }
    }
}

extern "C" void kernel_launch(void* const* d_in, const int* in_sizes, int n_in,
                              void* d_out, int out_size, void* d_ws, size_t ws_size,
                              hipStream_t stream) {
    const float* labels = (const float*)d_in[0];
    const float* z      = (const float*)d_in[1];
    const int*   di     = (const int*)d_in[2];
    const float* mask   = (const float*)d_in[3];
    const float* emb    = (const float*)d_in[4];
    const float* W1     = (const float*)d_in[5];
    const float* b1     = (const float*)d_in[6];
    const float* g1k    = (const float*)d_in[7];
    const float* g1rk   = (const float*)d_in[8];
    const float* g1b    = (const float*)d_in[9];
    const float* pW     = (const float*)d_in[10];
    const float* pb     = (const float*)d_in[11];

    char* ws = (char*)d_ws;
    float*           xp   = (float*)ws;                         // 34,406,400 B
    __hip_bfloat16*  g    = (__hip_bfloat16*)(ws + 34406400);   //  5,767,168 B
    __hip_bfloat16*  Wb   = (__hip_bfloat16*)(ws + 40173568);   // 45,056,000 B
    float*           hbuf = (float*)(ws + 85229568);            //    180,224 B
    unsigned*        flags= (unsigned*)(ws + 85409792);         //     11,200 B

    hipMemsetAsync(flags, 0, NBLK * FSTR * sizeof(unsigned), stream);

    wconv_kernel<<<dim3(1000, 22), dim3(32, 8), 0, stream>>>(pW, Wb);
    xp_kernel<<<dim3(4096), 256, 0, stream>>>(di, emb, g1k, g1b, xp);

    hipFuncSetAttribute((const void*)gru_kernel,
                        hipFuncAttributeMaxDynamicSharedMemorySize, 150016);
    gru_kernel<<<dim3(NBLK), 256, 150016, stream>>>(labels, z, W1, b1, xp, mask,
                                                    g1rk, g1b, hbuf, g, flags);

    gemm_kernel<<<dim3(250, 32), 256, 0, stream>>>(g, Wb, pb, (float*)d_out);
}

// Round 3
// 1477.130 us; speedup vs baseline: 2.8934x; 1.5641x over previous
//
#include <hip/hip_runtime.h>
#include <hip/hip_bf16.h>

#define B_   32
#define T_   128
#define H_   700
#define HP   704
#define E_   100
#define G3   2100
#define V_   32000
#define DY_  200
#define DZ_  500
#define KP   704
#define NBLK 175
#define JW   4
#define FSTR 16   // flag stride in uints (64B): one cacheline per flag

typedef __attribute__((ext_vector_type(8))) short bf16x8;
typedef __attribute__((ext_vector_type(4))) float f32x4;

__device__ __forceinline__ unsigned ld_flag(const unsigned* p) {
    return __hip_atomic_load(p, __ATOMIC_RELAXED, __HIP_MEMORY_SCOPE_AGENT);
}
__device__ __forceinline__ void st_flag(unsigned* p, unsigned v) {
    __hip_atomic_store(p, v, __ATOMIC_RELAXED, __HIP_MEMORY_SCOPE_AGENT);
}
__device__ __forceinline__ void st_h(float* p, float v) {
    __hip_atomic_store(p, v, __ATOMIC_RELAXED, __HIP_MEMORY_SCOPE_AGENT);
}
__device__ __forceinline__ unsigned long long ld_h8(const unsigned long long* p) {
    return __hip_atomic_load(p, __ATOMIC_RELAXED, __HIP_MEMORY_SCOPE_AGENT);
}

// ---------------- proj_W [700][32000] fp32 -> Wb [32000][704] bf16 (transposed, K-padded) ----------------
__global__ __launch_bounds__(256)
void wconv_kernel(const float* __restrict__ W, __hip_bfloat16* __restrict__ Wb) {
    __shared__ float tile[32][33];
    const int n0 = blockIdx.x * 32, k0 = blockIdx.y * 32;
    const int tx = threadIdx.x, ty = threadIdx.y;  // 32, 8
    #pragma unroll
    for (int i = 0; i < 4; ++i) {
        int k = k0 + ty + 8 * i;
        float v = (k < H_) ? W[(size_t)k * V_ + n0 + tx] : 0.0f;
        tile[ty + 8 * i][tx] = v;
    }
    __syncthreads();
    #pragma unroll
    for (int i = 0; i < 4; ++i) {
        int nn = ty + 8 * i;
        Wb[(size_t)(n0 + nn) * KP + k0 + tx] = __float2bfloat16(tile[tx][nn]);
    }
}

// ---------------- xp[b*T+t][2100] = emb[dec[b][t]] @ gru1_k + gru1_b[0]; also zero g pad cols ----------------
__global__ __launch_bounds__(256)
void xp_kernel(const int* __restrict__ di, const float* __restrict__ emb,
               const float* __restrict__ gk, const float* __restrict__ gb,
               float* __restrict__ xp, __hip_bfloat16* __restrict__ g_out) {
    __shared__ float xl[E_];
    const int row = blockIdx.x;
    const int tid = threadIdx.x;
    if (tid < E_) xl[tid] = emb[(size_t)di[row] * E_ + tid];
    if (tid < KP - H_) g_out[(size_t)row * KP + H_ + tid] = __float2bfloat16(0.0f);
    __syncthreads();
    for (int j4 = tid; j4 < G3 / 4; j4 += 256) {
        int j = j4 * 4;
        float4 a = *(const float4*)&gb[j];
        #pragma unroll 4
        for (int k = 0; k < E_; ++k) {
            float xv = xl[k];
            float4 wv = *(const float4*)&gk[(size_t)k * G3 + j];
            a.x += xv * wv.x; a.y += xv * wv.y; a.z += xv * wv.z; a.w += xv * wv.w;
        }
        *(float4*)&xp[(size_t)row * G3 + j] = a;
    }
}

// ---------------- persistent GRU recurrence ----------------
// 175 blocks x 256 threads, 1 block/CU (150KB LDS) -> co-resident.
// Block owns 4 gate indices (12 rk columns), all 32 batch rows.
// Sync: per-block monotonic flags; h exchanged via agent-scope (sc1) loads/stores
// that bypass L1/L2 and meet at the coherence point -> NO threadfence needed,
// L1/L2 stay warm for immutable inputs.
__global__ __launch_bounds__(256, 1)
void gru_kernel(const float* __restrict__ labels, const float* __restrict__ zin,
                const float* __restrict__ W1, const float* __restrict__ b1,
                const float* __restrict__ xp, const float* __restrict__ mask,
                const float* __restrict__ rk, const float* __restrict__ gb,
                float* __restrict__ hbuf, __hip_bfloat16* __restrict__ g_out,
                unsigned* __restrict__ flags) {
    extern __shared__ float sm[];
    float* h_lds  = sm;               // 32*704 = 22528 floats (swizzled)
    float* rk_lds = sm + 22528;       // 12*704 =  8448 floats
    float* part   = sm + 30976;       // 16*384 =  6144 floats
    float* hp_lds = sm + 37120;       // 384 floats

    const int tid = threadIdx.x;
    const int blk = blockIdx.x;
    const int j0  = blk * JW;

    // stage rk columns into LDS once (zero K-pad)
    for (int e = tid; e < 12 * HP; e += 256) {
        int c = e % 12, k = e / 12;
        int gcol = (c >> 2) * H_ + j0 + (c & 3);
        float v = (k < H_) ? rk[(size_t)k * G3 + gcol] : 0.0f;
        rk_lds[c * HP + k] = v;
    }

    // init h0 into hbuf[0] (sc1 stores -> visible at coherence point)
    if (tid < 128) {
        int b = tid >> 2, jj = tid & 3, j = j0 + jj;
        float v = (j < DY_) ? labels[b] * W1[j] + b1[j] : zin[b * DZ_ + (j - DY_)];
        st_h(&hbuf[b * HP + j], v);
    }
    if (blk == 0) {  // zero K-pads of both h buffers
        int buf = tid >> 7, rem = tid & 127, b = rem >> 2, p = rem & 3;
        st_h(&hbuf[buf * B_ * HP + b * HP + H_ + p], 0.0f);
    }

    // hoist step-invariant gate biases
    float bz = 0.f, brr = 0.f, bh = 0.f;
    if (tid < 128) {
        int j = j0 + (tid & 3);
        bz  = gb[G3 + j];
        brr = gb[G3 + H_ + j];
        bh  = gb[G3 + 2 * H_ + j];
    }

    __syncthreads();                         // drains vmcnt(0): h0 stores complete
    if (tid == 0) st_flag(&flags[blk * FSTR], 1u);

    const int kc = tid >> 4;          // 0..15 : K-chunk of 44
    const int u  = tid & 15;
    const int b0 = (u >> 1) * 4;      // 4-row tile
    const int c0 = (u & 1) * 6;       // 6-col tile
    const int kbeg = kc * 44;

    for (int step = 0; step < T_; ++step) {
        const int cur = step & 1, nxt = cur ^ 1;
        const unsigned long long* hg8 =
            (const unsigned long long*)(hbuf + cur * B_ * HP);

        // prefetch step-dependent immutable inputs (L1/L2-cached, never invalidated)
        float xz = 0.f, xr = 0.f, xh = 0.f, mv = 0.f;
        if (tid < 128) {
            int b = tid >> 2, j = j0 + (tid & 3);
            size_t xrow = (size_t)(b * T_ + step) * G3;
            xz = xp[xrow + j];
            xr = xp[xrow + H_ + j];
            xh = xp[xrow + 2 * H_ + j];
            mv = mask[(size_t)(b * T_ + step) * H_ + j];
        }

        // wait until every block published h_step (parallel, uncontended sc1 spins)
        if (tid < NBLK) {
            while (ld_flag(&flags[tid * FSTR]) < (unsigned)(step + 1))
                __builtin_amdgcn_s_sleep(1);
        }
        __syncthreads();

        // stage h via coherent 8B loads, batched for vmcnt pipelining,
        // then swizzled LDS writes (XOR bits 2..4 of float index by b>>2)
        unsigned long long tmp[44];
        #pragma unroll
        for (int i = 0; i < 44; ++i)
            tmp[i] = ld_h8(&hg8[tid + 256 * i]);
        #pragma unroll
        for (int i = 0; i < 44; ++i) {
            int e2 = (tid + 256 * i) * 2;          // float index, even
            int b = e2 / HP;
            int idx = e2 ^ ((b >> 2) << 2);
            *(unsigned long long*)&h_lds[idx] = tmp[i];
        }
        __syncthreads();

        // partial dots: 4 rows x 6 cols per thread over 44 K
        float acc[4][6];
        #pragma unroll
        for (int i = 0; i < 4; ++i)
            #pragma unroll
            for (int j = 0; j < 6; ++j) acc[i][j] = 0.0f;

        for (int k = kbeg; k < kbeg + 44; k += 4) {
            float4 hv[4], rv[6];
            #pragma unroll
            for (int i = 0; i < 4; ++i) {
                int b = b0 + i;
                hv[i] = *(const float4*)&h_lds[(b * HP + k) ^ ((b >> 2) << 2)];
            }
            #pragma unroll
            for (int j = 0; j < 6; ++j)
                rv[j] = *(const float4*)&rk_lds[(c0 + j) * HP + k];
            #pragma unroll
            for (int i = 0; i < 4; ++i)
                #pragma unroll
                for (int j = 0; j < 6; ++j)
                    acc[i][j] += hv[i].x * rv[j].x + hv[i].y * rv[j].y
                               + hv[i].z * rv[j].z + hv[i].w * rv[j].w;
        }
        #pragma unroll
        for (int i = 0; i < 4; ++i)
            #pragma unroll
            for (int j = 0; j < 6; ++j)
                part[kc * 384 + (b0 + i) * 12 + (c0 + j)] = acc[i][j];
        __syncthreads();

        // reduce K-chunks
        for (int d = tid; d < 384; d += 256) {
            float s = 0.0f;
            #pragma unroll
            for (int q = 0; q < 16; ++q) s += part[q * 384 + d];
            hp_lds[d] = s;
        }
        __syncthreads();

        // gates: 128 (b,j) pairs
        if (tid < 128) {
            int b = tid >> 2, jj = tid & 3, j = j0 + jj;
            float hpz = hp_lds[b * 12 + jj]      + bz;
            float hpr = hp_lds[b * 12 + 4 + jj]  + brr;
            float hph = hp_lds[b * 12 + 8 + jj]  + bh;
            float hold = h_lds[(b * HP + j) ^ ((b >> 2) << 2)];
            float zg = 1.0f / (1.0f + expf(-(xz + hpz)));
            float rg = 1.0f / (1.0f + expf(-(xr + hpr)));
            float hh = tanhf(xh + rg * hph);
            float hn = zg * hold + (1.0f - zg) * hh;
            st_h(&hbuf[nxt * B_ * HP + b * HP + j], hn);
            g_out[(size_t)(b * T_ + step) * KP + j] = __float2bfloat16(hn * mv);
        }
        __syncthreads();                    // drains vmcnt(0): h stores complete
        if (tid == 0) st_flag(&flags[blk * FSTR], (unsigned)(step + 2));
    }
}

// ---------------- projection GEMM: C[4096][32000] = g[4096][704] @ Wb[32000][704]^T + bias ----------------
__global__ __launch_bounds__(256)
void gemm_kernel(const __hip_bfloat16* __restrict__ A, const __hip_bfloat16* __restrict__ Bw,
                 const float* __restrict__ bias, float* __restrict__ C) {
    __shared__ alignas(16) unsigned short As[128][72];
    __shared__ alignas(16) unsigned short Bs[128][72];
    const int tid = threadIdx.x;
    const int bn = blockIdx.x, bm = blockIdx.y;
    const int rowbase = bm * 128, colbase = bn * 128;
    const int lane = tid & 63, w = tid >> 6;
    const int wm = w >> 1, wn = w & 1;
    const int lr = lane & 15, lkg = lane >> 4;

    f32x4 acc[4][4];
    #pragma unroll
    for (int i = 0; i < 4; ++i)
        #pragma unroll
        for (int j = 0; j < 4; ++j) acc[i][j] = (f32x4){0.f, 0.f, 0.f, 0.f};

    const int srow = tid >> 3, skk = (tid & 7) * 8;

    for (int kt = 0; kt < 11; ++kt) {
        const int k0 = kt * 64;
        __syncthreads();
        #pragma unroll
        for (int i = 0; i < 4; ++i) {
            int r = srow + i * 32;
            *(uint4*)&As[r][skk] = *(const uint4*)&A[(size_t)(rowbase + r) * KP + k0 + skk];
            *(uint4*)&Bs[r][skk] = *(const uint4*)&Bw[(size_t)(colbase + r) * KP + k0 + skk];
        }
        __syncthreads();
        #pragma unroll
        for (int ks = 0; ks < 2; ++ks) {
            bf16x8 af[4], bf[4];
            #pragma unroll
            for (int i = 0; i < 4; ++i)
                af[i] = *(const bf16x8*)&As[wm * 64 + i * 16 + lr][ks * 32 + lkg * 8];
            #pragma unroll
            for (int j = 0; j < 4; ++j)
                bf[j] = *(const bf16x8*)&Bs[wn * 64 + j * 16 + lr][ks * 32 + lkg * 8];
            #pragma unroll
            for (int i = 0; i < 4; ++i)
                #pragma unroll
                for (int j = 0; j < 4; ++j)
                    acc[i][j] = __builtin_amdgcn_mfma_f32_16x16x32_bf16(af[i], bf[j], acc[i][j], 0, 0, 0);
        }
    }

    float bv[4];
    #pragma unroll
    for (int j = 0; j < 4; ++j) bv[j] = bias[colbase + wn * 64 + j * 16 + lr];
    #pragma unroll
    for (int i = 0; i < 4; ++i) {
        int grow0 = rowbase + wm * 64 + i * 16 + lkg * 4;
        #pragma unroll
        for (int j = 0; j < 4; ++j) {
            int gcol = colbase + wn * 64 + j * 16 + lr;
            #pragma unroll
            for (int r = 0; r < 4; ++r)
                C[(size_t)(grow0 + r) * V_ + gcol] = acc[i][j][r] + bv[j];
        }
    }
}

extern "C" void kernel_launch(void* const* d_in, const int* in_sizes, int n_in,
                              void* d_out, int out_size, void* d_ws, size_t ws_size,
                              hipStream_t stream) {
    const float* labels = (const float*)d_in[0];
    const float* z      = (const float*)d_in[1];
    const int*   di     = (const int*)d_in[2];
    const float* mask   = (const float*)d_in[3];
    const float* emb    = (const float*)d_in[4];
    const float* W1     = (const float*)d_in[5];
    const float* b1     = (const float*)d_in[6];
    const float* g1k    = (const float*)d_in[7];
    const float* g1rk   = (const float*)d_in[8];
    const float* g1b    = (const float*)d_in[9];
    const float* pW     = (const float*)d_in[10];
    const float* pb     = (const float*)d_in[11];

    char* ws = (char*)d_ws;
    float*           xp   = (float*)ws;                         // 34,406,400 B
    __hip_bfloat16*  g    = (__hip_bfloat16*)(ws + 34406400);   //  5,767,168 B
    __hip_bfloat16*  Wb   = (__hip_bfloat16*)(ws + 40173568);   // 45,056,000 B
    float*           hbuf = (float*)(ws + 85229568);            //    180,224 B
    unsigned*        flags= (unsigned*)(ws + 85409792);         //     11,200 B

    hipMemsetAsync(flags, 0, NBLK * FSTR * sizeof(unsigned), stream);

    wconv_kernel<<<dim3(1000, 22), dim3(32, 8), 0, stream>>>(pW, Wb);
    xp_kernel<<<dim3(4096), 256, 0, stream>>>(di, emb, g1k, g1b, xp, g);

    hipFuncSetAttribute((const void*)gru_kernel,
                        hipFuncAttributeMaxDynamicSharedMemorySize, 150016);
    gru_kernel<<<dim3(NBLK), 256, 150016, stream>>>(labels, z, W1, b1, xp, mask,
                                                    g1rk, g1b, hbuf, g, flags);

    gemm_kernel<<<dim3(250, 32), 256, 0, stream>>>(g, Wb, pb, (float*)d_out);
}

// Round 4
// 1418.607 us; speedup vs baseline: 3.0128x; 1.0413x over previous
//
#include <hip/hip_runtime.h>
#include <hip/hip_bf16.h>

#define B_   32
#define T_   128
#define H_   700
#define HP2  768          // h K-pad for 16x16x32 MFMA tiling (4 waves x 6 tiles x 32)
#define E_   100
#define G3   2100
#define V_   32000
#define DY_  200
#define DZ_  500
#define KP   704          // g / Wb K-pad for projection GEMM
#define NBLK 175
#define JW   4
#define FSTR 16
#define BT   4096         // B_*T_

typedef __attribute__((ext_vector_type(8))) short bf16x8;
typedef __attribute__((ext_vector_type(4))) float f32x4;

__device__ __forceinline__ unsigned ld_flag(const unsigned* p) {
    return __hip_atomic_load(p, __ATOMIC_RELAXED, __HIP_MEMORY_SCOPE_AGENT);
}
__device__ __forceinline__ void st_flag(unsigned* p, unsigned v) {
    __hip_atomic_store(p, v, __ATOMIC_RELAXED, __HIP_MEMORY_SCOPE_AGENT);
}
__device__ __forceinline__ void st_h(float* p, float v) {
    __hip_atomic_store(p, v, __ATOMIC_RELAXED, __HIP_MEMORY_SCOPE_AGENT);
}
__device__ __forceinline__ unsigned long long ld_h8(const unsigned long long* p) {
    return __hip_atomic_load(p, __ATOMIC_RELAXED, __HIP_MEMORY_SCOPE_AGENT);
}
// split fp32 into bf16 hi + bf16 lo (residual); hi+lo ~ 16-bit-mantissa accurate
__device__ __forceinline__ void split_bf(float v, short& hi, short& lo) {
    __hip_bfloat16 h = __float2bfloat16(v);
    float r = v - __bfloat162float(h);
    __hip_bfloat16 l = __float2bfloat16(r);
    hi = *reinterpret_cast<short*>(&h);
    lo = *reinterpret_cast<short*>(&l);
}

// ---------------- proj_W [700][32000] fp32 -> Wb [32000][704] bf16 ----------------
__global__ __launch_bounds__(256)
void wconv_kernel(const float* __restrict__ W, __hip_bfloat16* __restrict__ Wb) {
    __shared__ float tile[32][33];
    const int n0 = blockIdx.x * 32, k0 = blockIdx.y * 32;
    const int tx = threadIdx.x, ty = threadIdx.y;
    #pragma unroll
    for (int i = 0; i < 4; ++i) {
        int k = k0 + ty + 8 * i;
        float v = (k < H_) ? W[(size_t)k * V_ + n0 + tx] : 0.0f;
        tile[ty + 8 * i][tx] = v;
    }
    __syncthreads();
    #pragma unroll
    for (int i = 0; i < 4; ++i) {
        int nn = ty + 8 * i;
        Wb[(size_t)(n0 + nn) * KP + k0 + tx] = __float2bfloat16(tile[tx][nn]);
    }
}

// ---------------- xp[b*T+t][2100] = emb[dec[b][t]] @ gru1_k + gru1_b[0]; zero g pads ----------------
__global__ __launch_bounds__(256)
void xp_kernel(const int* __restrict__ di, const float* __restrict__ emb,
               const float* __restrict__ gk, const float* __restrict__ gb,
               float* __restrict__ xp, __hip_bfloat16* __restrict__ g_out) {
    __shared__ float xl[E_];
    const int row = blockIdx.x;
    const int tid = threadIdx.x;
    if (tid < E_) xl[tid] = emb[(size_t)di[row] * E_ + tid];
    if (tid < KP - H_) g_out[(size_t)row * KP + H_ + tid] = __float2bfloat16(0.0f);
    __syncthreads();
    for (int j4 = tid; j4 < G3 / 4; j4 += 256) {
        int j = j4 * 4;
        float4 a = *(const float4*)&gb[j];
        #pragma unroll 4
        for (int k = 0; k < E_; ++k) {
            float xv = xl[k];
            float4 wv = *(const float4*)&gk[(size_t)k * G3 + j];
            a.x += xv * wv.x; a.y += xv * wv.y; a.z += xv * wv.z; a.w += xv * wv.w;
        }
        *(float4*)&xp[(size_t)row * G3 + j] = a;
    }
}

// ---------------- xp[bt][c] -> xp_t[c][t*32+b] ----------------
__global__ __launch_bounds__(256)
void xpt_kernel(const float* __restrict__ xp, float* __restrict__ xpt) {
    __shared__ float tl[32][33];
    const int c0 = blockIdx.x * 32, t = blockIdx.y;
    const int tx = threadIdx.x, ty = threadIdx.y;
    #pragma unroll
    for (int i = 0; i < 4; ++i) {
        int b = ty + 8 * i, c = c0 + tx;
        tl[b][tx] = (c < G3) ? xp[(size_t)(b * T_ + t) * G3 + c] : 0.0f;
    }
    __syncthreads();
    #pragma unroll
    for (int i = 0; i < 4; ++i) {
        int cc = ty + 8 * i;
        if (c0 + cc < G3)
            xpt[(size_t)(c0 + cc) * BT + t * 32 + tx] = tl[tx][cc];
    }
}

// ---------------- mask[b][t][j] -> mask_t[j][t*32+b] (bf16; mask in {0,2} exact) ----------------
__global__ __launch_bounds__(256)
void maskt_kernel(const float* __restrict__ mask, __hip_bfloat16* __restrict__ mkt) {
    __shared__ float tl[32][33];
    const int j0 = blockIdx.x * 32, t = blockIdx.y;
    const int tx = threadIdx.x, ty = threadIdx.y;
    #pragma unroll
    for (int i = 0; i < 4; ++i) {
        int b = ty + 8 * i, j = j0 + tx;
        tl[b][tx] = (j < H_) ? mask[(size_t)(b * T_ + t) * H_ + j] : 0.0f;
    }
    __syncthreads();
    #pragma unroll
    for (int i = 0; i < 4; ++i) {
        int cc = ty + 8 * i;
        if (j0 + cc < H_)
            mkt[(size_t)(j0 + cc) * BT + t * 32 + tx] = __float2bfloat16(tl[tx][cc]);
    }
}

// ---------------- persistent GRU, MFMA hi/lo recurrence ----------------
// 175 blocks x 256 threads (4 waves). Block owns 4 gate j's (12 rk cols -> 16-col B tile).
// Wave w owns K-range [w*192,(w+1)*192) = 6 K-tiles of 32. rk B-frags live in registers
// (hi/lo bf16). h A-frags load straight from coherent hbuf (sc1), split hi/lo, 3 MFMA
// passes (hi*hi + hi*lo + lo*hi) give ~fp32 accuracy. Cross-wave K-reduce via small LDS.
__global__ __launch_bounds__(256, 1)
void gru_kernel(const float* __restrict__ labels, const float* __restrict__ zin,
                const float* __restrict__ W1, const float* __restrict__ b1,
                const float* __restrict__ xpt, const __hip_bfloat16* __restrict__ mkt,
                const float* __restrict__ rk, const float* __restrict__ gb,
                float* __restrict__ hbuf, __hip_bfloat16* __restrict__ g_out,
                unsigned* __restrict__ flags) {
    __shared__ float part2[4 * 2 * 16 * 17];   // [w][m][row][col] pad17
    __shared__ float xb_z[128], xb_r[128], xb_h[128], xb_m[128];

    const int tid = threadIdx.x;
    const int blk = blockIdx.x;
    const int j0  = blk * JW;
    const int wv = tid >> 6, lane = tid & 63, lr = lane & 15, lkg = lane >> 4;

    // rk B-frags in registers, hi/lo (col = lr: c = gate*4+jj; k = wv*192 + t*32 + lkg*8 + i)
    bf16x8 rkb_hi[6], rkb_lo[6];
    const int gcol = (lr < 12) ? ((lr >> 2) * H_ + j0 + (lr & 3)) : 0;
    #pragma unroll
    for (int t = 0; t < 6; ++t) {
        #pragma unroll
        for (int i = 0; i < 8; ++i) {
            int k = wv * 192 + t * 32 + lkg * 8 + i;
            float v = (lr < 12 && k < H_) ? rk[(size_t)k * G3 + gcol] : 0.0f;
            short hi, lo; split_bf(v, hi, lo);
            rkb_hi[t][i] = hi; rkb_lo[t][i] = lo;
        }
    }

    // h0 init; own h carried in register
    float hold = 0.0f;
    if (tid < 128) {
        int b = tid >> 2, jj = tid & 3, j = j0 + jj;
        float v = (j < DY_) ? labels[b] * W1[j] + b1[j] : zin[b * DZ_ + (j - DY_)];
        hold = v;
        st_h(&hbuf[b * HP2 + j], v);
    }
    if (blk == 0) {  // zero K-pads [700,768) of both buffers
        for (int e = tid; e < 2 * B_ * (HP2 - H_); e += 256) {
            int buf = e / (B_ * (HP2 - H_)); int r = e % (B_ * (HP2 - H_));
            int b = r / (HP2 - H_), p = r % (HP2 - H_);
            st_h(&hbuf[buf * B_ * HP2 + b * HP2 + H_ + p], 0.0f);
        }
    }
    float bz = 0.f, brr = 0.f, bh = 0.f;
    if (tid < 128) {
        int j = j0 + (tid & 3);
        bz = gb[G3 + j]; brr = gb[G3 + H_ + j]; bh = gb[G3 + 2 * H_ + j];
    }
    __syncthreads();                       // drains vmcnt: h0 stores complete
    if (tid == 0) st_flag(&flags[blk * FSTR], 1u);

    union U64 { unsigned long long u; float f[2]; };

    for (int step = 0; step < T_; ++step) {
        const int cur = step & 1, nxt = cur ^ 1;
        const float* hg = hbuf + cur * B_ * HP2;

        // phase 1: prefetch x/mask (coalesced 128B lines, this block's exclusive cols)
        if (tid < 128) {
            int b = tid & 31, jl = tid >> 5;
            int jc = j0 + jl;
            xb_z[tid] = xpt[(size_t)(0 * H_ + jc) * BT + step * 32 + b];
            xb_r[tid] = xpt[(size_t)(1 * H_ + jc) * BT + step * 32 + b];
            xb_h[tid] = xpt[(size_t)(2 * H_ + jc) * BT + step * 32 + b];
            xb_m[tid] = __bfloat162float(mkt[(size_t)jc * BT + step * 32 + b]);
        }
        // phase 2: wait for all blocks' h_step
        if (tid < NBLK) {
            while (ld_flag(&flags[tid * FSTR]) < (unsigned)(step + 1))
                __builtin_amdgcn_s_sleep(1);
        }
        __syncthreads();

        // phase 3: load h A-frags (coherent 8B, all 48 in flight)
        U64 t64[48];
        #pragma unroll
        for (int m = 0; m < 2; ++m)
            #pragma unroll
            for (int t = 0; t < 6; ++t)
                #pragma unroll
                for (int q = 0; q < 4; ++q) {
                    int row = m * 16 + lr;
                    int k = wv * 192 + t * 32 + lkg * 8 + q * 2;
                    t64[(m * 6 + t) * 4 + q].u =
                        ld_h8((const unsigned long long*)&hg[row * HP2 + k]);
                }

        // phase 4: split hi/lo + MFMA (3 passes)
        f32x4 acc[2] = {(f32x4){0.f,0.f,0.f,0.f}, (f32x4){0.f,0.f,0.f,0.f}};
        #pragma unroll
        for (int m = 0; m < 2; ++m) {
            bf16x8 ahi[6], alo[6];
            #pragma unroll
            for (int t = 0; t < 6; ++t)
                #pragma unroll
                for (int q = 0; q < 4; ++q) {
                    U64 u = t64[(m * 6 + t) * 4 + q];
                    short h0, l0, h1, l1;
                    split_bf(u.f[0], h0, l0);
                    split_bf(u.f[1], h1, l1);
                    ahi[t][q * 2]     = h0; alo[t][q * 2]     = l0;
                    ahi[t][q * 2 + 1] = h1; alo[t][q * 2 + 1] = l1;
                }
            #pragma unroll
            for (int t = 0; t < 6; ++t) {
                acc[m] = __builtin_amdgcn_mfma_f32_16x16x32_bf16(ahi[t], rkb_hi[t], acc[m], 0, 0, 0);
                acc[m] = __builtin_amdgcn_mfma_f32_16x16x32_bf16(ahi[t], rkb_lo[t], acc[m], 0, 0, 0);
                acc[m] = __builtin_amdgcn_mfma_f32_16x16x32_bf16(alo[t], rkb_hi[t], acc[m], 0, 0, 0);
            }
        }
        // phase 5: per-wave partials to LDS (C layout: col=lane&15, row=(lane>>4)*4+r)
        #pragma unroll
        for (int m = 0; m < 2; ++m)
            #pragma unroll
            for (int r = 0; r < 4; ++r)
                part2[((wv * 2 + m) * 16 + lkg * 4 + r) * 17 + lr] = acc[m][r];
        __syncthreads();

        // phase 6: gates
        if (tid < 128) {
            int b = tid >> 2, jj = tid & 3, j = j0 + jj;
            int m = b >> 4, row = b & 15;
            float hpz = bz, hpr = brr, hph = bh;
            #pragma unroll
            for (int w = 0; w < 4; ++w) {
                int base = ((w * 2 + m) * 16 + row) * 17;
                hpz += part2[base + jj];
                hpr += part2[base + 4 + jj];
                hph += part2[base + 8 + jj];
            }
            int xi = jj * 32 + b;
            float xz = xb_z[xi], xr = xb_r[xi], xh = xb_h[xi], mv = xb_m[xi];
            float zg = 1.0f / (1.0f + expf(-(xz + hpz)));
            float rg = 1.0f / (1.0f + expf(-(xr + hpr)));
            float hh = tanhf(xh + rg * hph);
            float hn = zg * hold + (1.0f - zg) * hh;
            hold = hn;
            st_h(&hbuf[nxt * B_ * HP2 + b * HP2 + j], hn);
            g_out[(size_t)(b * T_ + step) * KP + j] = __float2bfloat16(hn * mv);
        }
        __syncthreads();                   // drains vmcnt: h stores complete
        if (tid == 0) st_flag(&flags[blk * FSTR], (unsigned)(step + 2));
    }
}

// ---------------- projection GEMM: C[4096][32000] = g @ Wb^T + bias ----------------
__global__ __launch_bounds__(256)
void gemm_kernel(const __hip_bfloat16* __restrict__ A, const __hip_bfloat16* __restrict__ Bw,
                 const float* __restrict__ bias, float* __restrict__ C) {
    __shared__ alignas(16) unsigned short As[128][72];
    __shared__ alignas(16) unsigned short Bs[128][72];
    const int tid = threadIdx.x;
    // bijective XCD-chunked swizzle: 8000 blocks = 8 XCDs x 1000; bn-major within chunk
    const int bid = blockIdx.x;
    const int co = (bid & 7) * 1000 + (bid >> 3);
    const int bm = co & 31, bn = co >> 5;
    const int rowbase = bm * 128, colbase = bn * 128;
    const int lane = tid & 63, w = tid >> 6;
    const int wm = w >> 1, wn = w & 1;
    const int lr = lane & 15, lkg = lane >> 4;

    f32x4 acc[4][4];
    #pragma unroll
    for (int i = 0; i < 4; ++i)
        #pragma unroll
        for (int j = 0; j < 4; ++j) acc[i][j] = (f32x4){0.f, 0.f, 0.f, 0.f};

    const int srow = tid >> 3, skk = (tid & 7) * 8;

    for (int kt = 0; kt < 11; ++kt) {
        const int k0 = kt * 64;
        __syncthreads();
        #pragma unroll
        for (int i = 0; i < 4; ++i) {
            int r = srow + i * 32;
            *(uint4*)&As[r][skk] = *(const uint4*)&A[(size_t)(rowbase + r) * KP + k0 + skk];
            *(uint4*)&Bs[r][skk] = *(const uint4*)&Bw[(size_t)(colbase + r) * KP + k0 + skk];
        }
        __syncthreads();
        #pragma unroll
        for (int ks = 0; ks < 2; ++ks) {
            bf16x8 af[4], bf[4];
            #pragma unroll
            for (int i = 0; i < 4; ++i)
                af[i] = *(const bf16x8*)&As[wm * 64 + i * 16 + lr][ks * 32 + lkg * 8];
            #pragma unroll
            for (int j = 0; j < 4; ++j)
                bf[j] = *(const bf16x8*)&Bs[wn * 64 + j * 16 + lr][ks * 32 + lkg * 8];
            #pragma unroll
            for (int i = 0; i < 4; ++i)
                #pragma unroll
                for (int j = 0; j < 4; ++j)
                    acc[i][j] = __builtin_amdgcn_mfma_f32_16x16x32_bf16(af[i], bf[j], acc[i][j], 0, 0, 0);
        }
    }

    float bv[4];
    #pragma unroll
    for (int j = 0; j < 4; ++j) bv[j] = bias[colbase + wn * 64 + j * 16 + lr];
    #pragma unroll
    for (int i = 0; i < 4; ++i) {
        int grow0 = rowbase + wm * 64 + i * 16 + lkg * 4;
        #pragma unroll
        for (int j = 0; j < 4; ++j) {
            int gcol = colbase + wn * 64 + j * 16 + lr;
            #pragma unroll
            for (int r = 0; r < 4; ++r)
                C[(size_t)(grow0 + r) * V_ + gcol] = acc[i][j][r] + bv[j];
        }
    }
}

extern "C" void kernel_launch(void* const* d_in, const int* in_sizes, int n_in,
                              void* d_out, int out_size, void* d_ws, size_t ws_size,
                              hipStream_t stream) {
    const float* labels = (const float*)d_in[0];
    const float* z      = (const float*)d_in[1];
    const int*   di     = (const int*)d_in[2];
    const float* mask   = (const float*)d_in[3];
    const float* emb    = (const float*)d_in[4];
    const float* W1     = (const float*)d_in[5];
    const float* b1     = (const float*)d_in[6];
    const float* g1k    = (const float*)d_in[7];
    const float* g1rk   = (const float*)d_in[8];
    const float* g1b    = (const float*)d_in[9];
    const float* pW     = (const float*)d_in[10];
    const float* pb     = (const float*)d_in[11];

    // ws: long-lived (GEMM-visible) buffers only (~51 MB)
    char* ws = (char*)d_ws;
    __hip_bfloat16* g    = (__hip_bfloat16*)ws;                    //  5,767,168 B
    __hip_bfloat16* Wb   = (__hip_bfloat16*)(ws + 5767168);        // 45,056,000 B
    float*          hbuf = (float*)(ws + 50823168);                //    196,608 B
    unsigned*       flags= (unsigned*)(ws + 51019776);             //     11,200 B

    // d_out doubles as scratch for GRU-phase-only data (dead before gemm writes C)
    char* ob = (char*)d_out;
    float*          xpt  = (float*)ob;                             // 34,406,400 B
    __hip_bfloat16* mkt  = (__hip_bfloat16*)(ob + 34406400);       //  5,734,400 B
    float*          xp   = (float*)(ob + 40140800);                // 34,406,400 B

    hipMemsetAsync(flags, 0, NBLK * FSTR * sizeof(unsigned), stream);

    wconv_kernel<<<dim3(1000, 22), dim3(32, 8), 0, stream>>>(pW, Wb);
    xp_kernel<<<dim3(4096), 256, 0, stream>>>(di, emb, g1k, g1b, xp, g);
    xpt_kernel<<<dim3(66, 128), dim3(32, 8), 0, stream>>>(xp, xpt);
    maskt_kernel<<<dim3(22, 128), dim3(32, 8), 0, stream>>>(mask, mkt);

    gru_kernel<<<dim3(NBLK), 256, 0, stream>>>(labels, z, W1, b1, xpt, mkt,
                                               g1rk, g1b, hbuf, g, flags);

    gemm_kernel<<<dim3(8000), 256, 0, stream>>>(g, Wb, pb, (float*)d_out);
}